// Round 11
// baseline (256.670 us; speedup 1.0000x reference)
//
#include <hip/hip_runtime.h>
#include <hip/hip_bf16.h>
#include <hip/hip_fp16.h>

// VSSBlock: B=2 H=64 W=64 C=192 DM=384 N=16 R=12 K=4 L=4096
// R19 (on R18 base, 236.5us): scans use segment-wide (delta,u) register preload —
//     16-step load bursts packed into unsigned regs (R15-loop1-verified mechanics,
//     affine p-walk), fully-unrolled compute (static reg indices). B|C stay as
//     per-lane VMEM broadcasts. Everything else identical to R18.

typedef __attribute__((ext_vector_type(8))) short short8;     // 8 bf16 = 4 VGPRs
typedef __attribute__((ext_vector_type(4))) float floatx4;    // fp32 accum frag

// ---------------- fused: LN (pre-norm, eps 1e-6) -> bf16  +  weight pack ----------------
__global__ __launch_bounds__(256) void k_lnpackw(const float* __restrict__ in,
                                                 const float* __restrict__ g,
                                                 const float* __restrict__ be,
                                                 __hip_bfloat16* __restrict__ out,
                                                 const float* __restrict__ ipw,
                                                 const float* __restrict__ xpw,
                                                 const float* __restrict__ opw,
                                                 __hip_bfloat16* __restrict__ Wt1,
                                                 __hip_bfloat16* __restrict__ Wt2,
                                                 __hip_bfloat16* __restrict__ Wt3) {
  int bid = blockIdx.x;
  if (bid < 2048) {                 // LayerNorm: 4 rows/block
    int row = bid * 4 + (threadIdx.x >> 6);
    int lane = threadIdx.x & 63;
    const float* x = in + (long)row * 192;
    float v0 = x[lane], v1 = x[lane + 64], v2 = x[lane + 128];
    float s = v0 + v1 + v2;
    float s2 = v0 * v0 + v1 * v1 + v2 * v2;
    #pragma unroll
    for (int o = 32; o > 0; o >>= 1) { s += __shfl_xor(s, o); s2 += __shfl_xor(s2, o); }
    float mu = s * (1.f / 192.f);
    float var = s2 * (1.f / 192.f) - mu * mu;
    float r = rsqrtf(var + 1e-6f);
    __hip_bfloat16* op = out + (long)row * 192;
    op[lane]       = __float2bfloat16((v0 - mu) * r * g[lane]       + be[lane]);
    op[lane + 64]  = __float2bfloat16((v1 - mu) * r * g[lane + 64]  + be[lane + 64]);
    op[lane + 128] = __float2bfloat16((v2 - mu) * r * g[lane + 128] + be[lane + 128]);
  } else {                          // weight pack
    int idx = (bid - 2048) * 256 + threadIdx.x;
    if (idx < 147456) {                       // Wt1[n][k] = ipw[k][n]
      int n = idx / 192, k = idx - n * 192;
      Wt1[idx] = __float2bfloat16(ipw[(long)k * 768 + n]);
    } else if (idx < 147456 + 73728) {        // Wt2[j][d]
      int t = idx - 147456;
      int j = t / 384;
      float v = (j < 176) ? xpw[t] : 0.f;
      Wt2[t] = __float2bfloat16(v);
    } else if (idx < 147456 + 73728 + 73728) {// Wt3[n][k] = opw[k][n]
      int t = idx - 147456 - 73728;
      int n = t / 384, k = t - n * 384;
      Wt3[t] = __float2bfloat16(opw[(long)k * 192 + n]);
    }
  }
}

// direction map (involutions): pixel p <-> scan position l
__device__ __forceinline__ int inv_dir(int k, int p) {
  int pt = ((p & 63) << 6) | (p >> 6);
  if (k == 0) return p;
  if (k == 1) return pt;
  if (k == 2) return 4095 - p;
  return 4095 - pt;
}
__device__ __forceinline__ int dir_pix(int k, int l) { return inv_dir(k, l); }

// ---------------- bf16 MFMA GEMM: 64xTN tile, BK=64, XOR-swizzled LDS ----------------
template <int EPI, int TN>
__global__ __launch_bounds__(256) void k_gemm_mfma(const __hip_bfloat16* __restrict__ A,
                                                   const __hip_bfloat16* __restrict__ Bt,
                                                   const float* __restrict__ Res,
                                                   float* __restrict__ Co,
                                                   __hip_bfloat16* __restrict__ CoB,
                                                   __hip_bfloat16* __restrict__ Co2B,
                                                   float* __restrict__ dtsS,
                                                   float* __restrict__ BCs,
                                                   int M, int N, int Kk) {
  constexpr int NI = TN / 32;
  __shared__ __align__(16) short As[64 * 64];
  __shared__ __align__(16) short Bs[TN * 64];
  int tid = threadIdx.x;
  int wave = tid >> 6, lane = tid & 63;
  int mlane = lane & 15, quad = lane >> 4;
  int row0 = blockIdx.y * 64, col0 = blockIdx.x * TN;
  int wr = wave & 1, wc = wave >> 1;
  floatx4 acc[2][NI];
  #pragma unroll
  for (int mi = 0; mi < 2; mi++)
    #pragma unroll
    for (int ni = 0; ni < NI; ni++) acc[mi][ni] = (floatx4){0.f, 0.f, 0.f, 0.f};

  for (int k0 = 0; k0 < Kk; k0 += 64) {
    #pragma unroll
    for (int c = tid; c < 512; c += 256) {
      int r = c >> 3, j = c & 7;
      *(float4*)&As[r * 64 + ((j ^ (r & 7)) << 3)] =
          *(const float4*)&A[(long)(row0 + r) * Kk + k0 + j * 8];
    }
    #pragma unroll
    for (int c = tid; c < TN * 8; c += 256) {
      int r = c >> 3, j = c & 7;
      *(float4*)&Bs[r * 64 + ((j ^ (r & 7)) << 3)] =
          *(const float4*)&Bt[(long)(col0 + r) * Kk + k0 + j * 8];
    }
    __syncthreads();
    short8 af[2][2], bf[NI][2];
    #pragma unroll
    for (int mi = 0; mi < 2; mi++) {
      int r = wr * 32 + mi * 16 + mlane;
      #pragma unroll
      for (int kk = 0; kk < 2; kk++) {
        int jx = (kk * 4 + quad) ^ (r & 7);
        af[mi][kk] = *(const short8*)&As[r * 64 + jx * 8];
      }
    }
    #pragma unroll
    for (int ni = 0; ni < NI; ni++) {
      int rn = wc * (TN / 2) + ni * 16 + mlane;
      #pragma unroll
      for (int kk = 0; kk < 2; kk++) {
        int jx = (kk * 4 + quad) ^ (rn & 7);
        bf[ni][kk] = *(const short8*)&Bs[rn * 64 + jx * 8];
      }
    }
    #pragma unroll
    for (int kk = 0; kk < 2; kk++)
      #pragma unroll
      for (int mi = 0; mi < 2; mi++)
        #pragma unroll
        for (int ni = 0; ni < NI; ni++)
          acc[mi][ni] = __builtin_amdgcn_mfma_f32_16x16x32_bf16(af[mi][kk], bf[ni][kk],
                                                                acc[mi][ni], 0, 0, 0);
    __syncthreads();
  }
  // C/D layout: col=lane&15, row=quad*4+reg  [m89-verified]
  #pragma unroll
  for (int mi = 0; mi < 2; mi++) {
    #pragma unroll
    for (int ni = 0; ni < NI; ni++) {
      int cc = col0 + wc * (TN / 2) + ni * 16 + mlane;
      #pragma unroll
      for (int i = 0; i < 4; i++) {
        int rr = row0 + wr * 32 + mi * 16 + quad * 4 + i;
        float v = acc[mi][ni][i];
        if (EPI == 1) {
          Co[(long)rr * N + cc] = v + Res[(long)rr * N + cc];
        } else if (EPI == 2) {
          if (cc < 384) CoB[(long)rr * 384 + cc] = __float2bfloat16(v);
          else          Co2B[(long)rr * 384 + (cc - 384)] = __float2bfloat16(v);
        } else {  // EPI == 3: pixel-order split; B at 0..15, C at 16..31 of BCs row
          if (cc < 176) {
            int k4 = (cc >= 132) ? 3 : (cc >= 88) ? 2 : (cc >= 44) ? 1 : 0;
            int c = cc - k4 * 44;
            int b = rr >> 12, p = rr & 4095;
            long lbase = ((long)((b << 2) + k4) << 12) + p;   // pixel order
            if (c < 12) dtsS[lbase * 12 + c] = v;
            else        BCs[lbase * 32 + (c - 12)] = v;
          }
        }
      }
    }
  }
}

// ---------------- depthwise 3x3 conv + bias + SiLU; 2x4 pixels/block; bf16 in/out ----------------
__global__ __launch_bounds__(384) void k_conv(const __hip_bfloat16* __restrict__ xbufB,
                                              const float* __restrict__ cw,
                                              const float* __restrict__ cb,
                                              __hip_bfloat16* __restrict__ xcb) {
  int blk = blockIdx.x;            // 1024: b(2) x hgroup(32) x wgroup(16)
  int wg = blk & 15, hg = (blk >> 4) & 31, b = blk >> 9;
  int h0 = hg * 2, w0 = wg * 4;
  int d = threadIdx.x;
  float wt[9];
  const float* wp = cw + d * 9;
  #pragma unroll
  for (int i = 0; i < 9; i++) wt[i] = wp[i];
  float bias = cb[d];
  float v[4][6];
  #pragma unroll
  for (int r = 0; r < 4; r++) {
    int hh = h0 + r - 1;
    bool rok = (hh >= 0) && (hh < 64);
    #pragma unroll
    for (int c = 0; c < 6; c++) {
      int ww = w0 + c - 1;
      bool ok = rok && (ww >= 0) && (ww < 64);
      v[r][c] = ok ? __bfloat162float(xbufB[((long)(b << 12) + (hh << 6) + ww) * 384 + d]) : 0.f;
    }
  }
  #pragma unroll
  for (int i = 0; i < 2; i++) {
    #pragma unroll
    for (int j = 0; j < 4; j++) {
      float acc = bias;
      #pragma unroll
      for (int r = 0; r < 3; r++)
        #pragma unroll
        for (int c = 0; c < 3; c++)
          acc += v[i + r][j + c] * wt[r * 3 + c];
      float sg = 1.f / (1.f + __expf(-acc));
      xcb[((long)(b << 12) + ((h0 + i) << 6) + (w0 + j)) * 384 + d] = __float2bfloat16(acc * sg);
    }
  }
}

// ---------------- dt precompute: delta = softplus(dts @ dt_w^T + dt_b) -> fp16 plane ----------------
__global__ __launch_bounds__(384) void k_dt(const float* __restrict__ dtsS,
                                            const float* __restrict__ dt_w,
                                            const float* __restrict__ dt_b,
                                            __half* __restrict__ dpre) {
  int bid = blockIdx.x;
  int chunk = bid & 127, bk = bid >> 7;
  int k = bk & 3;
  int d = threadIdx.x;
  float w[12];
  const float* dwp = dt_w + ((long)(k * 384) + d) * 12;
  #pragma unroll
  for (int r = 0; r < 12; r++) w[r] = dwp[r];
  float db = dt_b[k * 384 + d];
  long base = ((long)bk << 12) + chunk * 32;
  #pragma unroll 4
  for (int t = 0; t < 32; t++) {
    const float4* dq = (const float4*)(dtsS + (base + t) * 12);
    float4 q0 = dq[0], q1 = dq[1], q2 = dq[2];
    float x = db + q0.x * w[0] + q0.y * w[1] + q0.z * w[2] + q0.w * w[3]
                 + q1.x * w[4] + q1.y * w[5] + q1.z * w[6] + q1.w * w[7]
                 + q2.x * w[8] + q2.y * w[9] + q2.z * w[10] + q2.w * w[11];
    float e = __expf(x);
    float delta = (x > 15.f) ? x : __logf(1.f + e);
    dpre[(base + t) * 384 + d] = __float2half(delta);
  }
}

// powers: pws[n] = r^(n+1), log-depth pairing
__device__ __forceinline__ void pow16(float r, float* pws) {
  pws[0] = r;
  #pragma unroll
  for (int n = 1; n < 16; n++) {
    int m = n + 1, c = (m + 1) / 2, f = m - c;
    pws[n] = pws[c - 1] * pws[f - 1];
  }
}

// ---------------- scan pass 0: 128 segments x 32 steps; (delta,u) preload bursts ----------------
__global__ __launch_bounds__(384) void k_scan0(
    const __half* __restrict__ dpre, const float* __restrict__ BCs,
    const __hip_bfloat16* __restrict__ xcb,
    const float* __restrict__ A_logs,
    __half* __restrict__ EbH, float* __restrict__ Dend) {
  int bid = blockIdx.x;
  int s = bid & 127, bk = bid >> 7;
  int k = bk & 3, b = bk >> 2;
  int d = threadIdx.x;
  const float* al = A_logs + ((long)(k * 384) + d) * 16;
  bool pw = true;
  float av[16];
  #pragma unroll
  for (int n = 0; n < 16; n++) {
    float a = __expf(al[n]);
    av[n] = -a;
    pw = pw && (fabsf(a - (float)(n + 1)) < 1e-3f);
  }
  float h[16];
  #pragma unroll
  for (int n = 0; n < 16; n++) h[n] = 0.f;
  float cum = 0.f;
  long bpk = (long)bk << 12;
  long bpix = (long)(b << 12);

  if (pw) {
    // affine pixel walk within a 32-step segment (valid for all 4 directions)
    int l0 = s * 32;
    int p0 = dir_pix(k, l0);
    int stride = dir_pix(k, l0 + 1) - p0;
    const unsigned short* dpu = (const unsigned short*)dpre;
    const unsigned short* xcu = (const unsigned short*)xcb;
    #pragma unroll
    for (int g = 0; g < 2; g++) {
      unsigned dpk[8], upk[8];
      #pragma unroll
      for (int tt = 0; tt < 16; tt++) {           // 32-load burst (16 delta + 16 u)
        int p = p0 + stride * (g * 16 + tt);
        unsigned hd = dpu[(bpk + p) * 384 + d];
        unsigned ub = xcu[(bpix + p) * 384 + d];
        if (tt & 1) { dpk[tt >> 1] |= hd << 16; upk[tt >> 1] |= ub << 16; }
        else        { dpk[tt >> 1] = hd;        upk[tt >> 1] = ub; }
      }
      #pragma unroll
      for (int tt = 0; tt < 16; tt++) {           // fully unrolled compute (static idx)
        int p = p0 + stride * (g * 16 + tt);
        unsigned wd = dpk[tt >> 1], wu = upk[tt >> 1];
        unsigned short hd = (tt & 1) ? (unsigned short)(wd >> 16) : (unsigned short)(wd & 0xffff);
        unsigned ub = (tt & 1) ? (wu >> 16) : (wu & 0xffff);
        float delta = __half2float(__ushort_as_half(hd));
        float u = __uint_as_float(ub << 16);
        cum += delta;
        float du = delta * u;
        float rr = __expf(-delta);
        float pws[16]; pow16(rr, pws);
        const float4* Bq = (const float4*)(BCs + (bpk + p) * 32);
        float4 b0 = Bq[0], b1 = Bq[1], b2 = Bq[2], b3 = Bq[3];
        float Bl[16] = {b0.x, b0.y, b0.z, b0.w, b1.x, b1.y, b1.z, b1.w,
                        b2.x, b2.y, b2.z, b2.w, b3.x, b3.y, b3.z, b3.w};
        #pragma unroll
        for (int n = 0; n < 16; n++) h[n] = pws[n] * h[n] + du * Bl[n];
      }
    }
  } else {
    for (int t = 0; t < 32; t++) {
      int p = dir_pix(k, s * 32 + t);
      float delta = __half2float(dpre[(bpk + p) * 384 + d]);
      float u = __bfloat162float(xcb[(bpix + p) * 384 + d]);
      cum += delta;
      float du = delta * u;
      const float4* Bq = (const float4*)(BCs + (bpk + p) * 32);
      float4 b0 = Bq[0], b1 = Bq[1], b2 = Bq[2], b3 = Bq[3];
      float Bl[16] = {b0.x, b0.y, b0.z, b0.w, b1.x, b1.y, b1.z, b1.w,
                      b2.x, b2.y, b2.z, b2.w, b3.x, b3.y, b3.z, b3.w};
      #pragma unroll
      for (int n = 0; n < 16; n++) {
        float dA = __expf(delta * av[n]);
        h[n] = dA * h[n] + du * Bl[n];
      }
    }
  }
  long g2 = (long)bk * 128 + s;
  __half2* Ep = (__half2*)(EbH + g2 * 6144 + (long)d * 16);
  #pragma unroll
  for (int n = 0; n < 8; n++) {
    __half2 hv;
    hv.x = __float2half(h[2 * n]);
    hv.y = __float2half(h[2 * n + 1]);
    Ep[n] = hv;
  }
  Dend[g2 * 384 + d] = cum;
}

// ---------------- combine: Kogge-Stone over 128 segments; fp16 I/O, fp32 internal ----------------
__global__ __launch_bounds__(128) void k_combine(__half* __restrict__ EbH,
                                                 const float* __restrict__ Dend,
                                                 const float* __restrict__ A_logs) {
  int bid = blockIdx.x;            // bk*384 + d, 3072 blocks
  int bk = bid / 384;
  int d = bid - bk * 384;
  int k = bk & 3;
  int s = threadIdx.x;             // segment 0..127
  const float* al = A_logs + ((long)(k * 384) + d) * 16;
  bool pw = true;
  float av[16];
  #pragma unroll
  for (int n = 0; n < 16; n++) {
    float a = __expf(al[n]);
    av[n] = -a;
    pw = pw && (fabsf(a - (float)(n + 1)) < 1e-3f);
  }

  long ebase = ((long)bk * 128 + s) * 6144 + (long)d * 16;
  float e[16];
  {
    const __half2* Ein = (const __half2*)(EbH + ebase);
    #pragma unroll
    for (int n = 0; n < 8; n++) {
      __half2 hv = Ein[n];
      e[2 * n]     = __half2float(hv.x);
      e[2 * n + 1] = __half2float(hv.y);
    }
  }
  float sig = Dend[((long)bk * 128 + s) * 384 + d];

  __shared__ float sE[128][17];    // [s][0]=sigma, [s][1..16]=e
  sE[s][0] = sig;
  #pragma unroll
  for (int n = 0; n < 16; n++) sE[s][1 + n] = e[n];
  __syncthreads();

  for (int o = 1; o < 128; o <<= 1) {
    float ps = 0.f, pe[16];
    bool act = (s >= o);
    if (act) {
      ps = sE[s - o][0];
      #pragma unroll
      for (int n = 0; n < 16; n++) pe[n] = sE[s - o][1 + n];
    }
    __syncthreads();
    if (act) {
      if (pw) {
        float rc = __expf(-sig);
        float pwr[16]; pow16(rc, pwr);      // pwr[n] = exp(av[n]*sig), av[n]=-(n+1)
        #pragma unroll
        for (int n = 0; n < 16; n++) e[n] += pwr[n] * pe[n];
      } else {
        #pragma unroll
        for (int n = 0; n < 16; n++) e[n] += __expf(av[n] * sig) * pe[n];
      }
      sig += ps;
      sE[s][0] = sig;
      #pragma unroll
      for (int n = 0; n < 16; n++) sE[s][1 + n] = e[n];
    }
    __syncthreads();
  }

  float ho[16];
  if (s == 0) {
    #pragma unroll
    for (int n = 0; n < 16; n++) ho[n] = 0.f;
  } else {
    #pragma unroll
    for (int n = 0; n < 16; n++) ho[n] = sE[s - 1][1 + n];
  }
  __half2* Eo = (__half2*)(EbH + ebase);
  #pragma unroll
  for (int n = 0; n < 8; n++) {
    __half2 hv;
    hv.x = __float2half(ho[2 * n]);
    hv.y = __float2half(ho[2 * n + 1]);
    Eo[n] = hv;
  }
}

// ---------------- scan pass 1: recurrence from h_in (fp16 EbH); (delta,u) preload ----------------
// ATOMIC=0: store y bf16 into per-direction plane ybufB. ATOMIC=1: fp32 atomicAdd ysum.
template <int ATOMIC>
__global__ __launch_bounds__(384) void k_scan1(
    const __half* __restrict__ dpre, const float* __restrict__ BCs,
    const __hip_bfloat16* __restrict__ xcb,
    const float* __restrict__ A_logs, const __half* __restrict__ EbH,
    __hip_bfloat16* __restrict__ ybufB, float* __restrict__ ysum) {
  int bid = blockIdx.x;
  int s = bid & 127, bk = bid >> 7;
  int k = bk & 3, b = bk >> 2;
  int d = threadIdx.x;
  const float* al = A_logs + ((long)(k * 384) + d) * 16;
  bool pw = true;
  float av[16];
  #pragma unroll
  for (int n = 0; n < 16; n++) {
    float a = __expf(al[n]);
    av[n] = -a;
    pw = pw && (fabsf(a - (float)(n + 1)) < 1e-3f);
  }
  float h[16];
  {
    const __half2* hp = (const __half2*)(EbH + ((long)bk * 128 + s) * 6144 + (long)d * 16);
    #pragma unroll
    for (int n = 0; n < 8; n++) {
      __half2 hv = hp[n];
      h[2 * n]     = __half2float(hv.x);
      h[2 * n + 1] = __half2float(hv.y);
    }
  }
  long bpk = (long)bk << 12;
  long bpix = (long)(b << 12);

  if (pw) {
    int l0 = s * 32;
    int p0 = dir_pix(k, l0);
    int stride = dir_pix(k, l0 + 1) - p0;
    const unsigned short* dpu = (const unsigned short*)dpre;
    const unsigned short* xcu = (const unsigned short*)xcb;
    #pragma unroll
    for (int g = 0; g < 2; g++) {
      unsigned dpk[8], upk[8];
      #pragma unroll
      for (int tt = 0; tt < 16; tt++) {           // 32-load burst
        int p = p0 + stride * (g * 16 + tt);
        unsigned hd = dpu[(bpk + p) * 384 + d];
        unsigned ub = xcu[(bpix + p) * 384 + d];
        if (tt & 1) { dpk[tt >> 1] |= hd << 16; upk[tt >> 1] |= ub << 16; }
        else        { dpk[tt >> 1] = hd;        upk[tt >> 1] = ub; }
      }
      #pragma unroll
      for (int tt = 0; tt < 16; tt++) {           // fully unrolled compute
        int p = p0 + stride * (g * 16 + tt);
        unsigned wd = dpk[tt >> 1], wu = upk[tt >> 1];
        unsigned short hd = (tt & 1) ? (unsigned short)(wd >> 16) : (unsigned short)(wd & 0xffff);
        unsigned ub = (tt & 1) ? (wu >> 16) : (wu & 0xffff);
        float delta = __half2float(__ushort_as_half(hd));
        float u = __uint_as_float(ub << 16);
        float du = delta * u;
        float rr = __expf(-delta);
        float pws[16]; pow16(rr, pws);
        const float4* Bq = (const float4*)(BCs + (bpk + p) * 32);
        float4 b0 = Bq[0], b1 = Bq[1], b2 = Bq[2], b3 = Bq[3];
        float Bl[16] = {b0.x, b0.y, b0.z, b0.w, b1.x, b1.y, b1.z, b1.w,
                        b2.x, b2.y, b2.z, b2.w, b3.x, b3.y, b3.z, b3.w};
        const float4* Cq = Bq + 4;
        float4 c0 = Cq[0], c1 = Cq[1], c2 = Cq[2], c3 = Cq[3];
        float Cl[16] = {c0.x, c0.y, c0.z, c0.w, c1.x, c1.y, c1.z, c1.w,
                        c2.x, c2.y, c2.z, c2.w, c3.x, c3.y, c3.z, c3.w};
        float y = 0.f;
        #pragma unroll
        for (int n = 0; n < 16; n++) { h[n] = pws[n] * h[n] + du * Bl[n]; y += h[n] * Cl[n]; }
        if (ATOMIC) atomicAdd(&ysum[(bpix + p) * 384 + d], y);
        else        ybufB[(bpk + p) * 384 + d] = __float2bfloat16(y);
      }
    }
  } else {
    for (int t = 0; t < 32; t++) {
      int p = dir_pix(k, s * 32 + t);
      float delta = __half2float(dpre[(bpk + p) * 384 + d]);
      float u = __bfloat162float(xcb[(bpix + p) * 384 + d]);
      float du = delta * u;
      const float4* Bq = (const float4*)(BCs + (bpk + p) * 32);
      float4 b0 = Bq[0], b1 = Bq[1], b2 = Bq[2], b3 = Bq[3];
      float Bl[16] = {b0.x, b0.y, b0.z, b0.w, b1.x, b1.y, b1.z, b1.w,
                      b2.x, b2.y, b2.z, b2.w, b3.x, b3.y, b3.z, b3.w};
      const float4* Cq = Bq + 4;
      float4 c0 = Cq[0], c1 = Cq[1], c2 = Cq[2], c3 = Cq[3];
      float Cl[16] = {c0.x, c0.y, c0.z, c0.w, c1.x, c1.y, c1.z, c1.w,
                      c2.x, c2.y, c2.z, c2.w, c3.x, c3.y, c3.z, c3.w};
      float y = 0.f;
      #pragma unroll
      for (int n = 0; n < 16; n++) {
        float dA = __expf(delta * av[n]);
        h[n] = dA * h[n] + du * Bl[n];
        y += h[n] * Cl[n];
      }
      if (ATOMIC) atomicAdd(&ysum[(bpix + p) * 384 + d], y);
      else        ybufB[(bpk + p) * 384 + d] = __float2bfloat16(y);
    }
  }
}

// ---------------- merge: y + D-skip(bf16 xcb) + out-LN + silu(z bf16) -> bf16 ----------------
template <int GATHER>
__global__ __launch_bounds__(384) void k_merge(const __hip_bfloat16* __restrict__ yinB,
                                               const float* __restrict__ yinF,
                                               const __hip_bfloat16* __restrict__ xcb,
                                               const __hip_bfloat16* __restrict__ zbufB,
                                               const float* __restrict__ Ds,
                                               const float* __restrict__ g,
                                               const float* __restrict__ be,
                                               __hip_bfloat16* __restrict__ yactb) {
  int row = blockIdx.x;
  int d = threadIdx.x;
  float v;
  if (GATHER) {
    int b = row >> 12, p = row & 4095;
    long base = ((long)(b << 2) << 12) + p;  // plane (b*4+k)*4096 + p
    v = __bfloat162float(yinB[base * 384 + d])
      + __bfloat162float(yinB[(base + 4096) * 384 + d])
      + __bfloat162float(yinB[(base + 8192) * 384 + d])
      + __bfloat162float(yinB[(base + 12288) * 384 + d]);
  } else {
    v = yinF[(long)row * 384 + d];
  }
  float sd = Ds[d] + Ds[384 + d] + Ds[768 + d] + Ds[1152 + d];
  v += __bfloat162float(xcb[(long)row * 384 + d]) * sd;
  float s1 = v, s2 = v * v;
  #pragma unroll
  for (int o = 32; o > 0; o >>= 1) { s1 += __shfl_xor(s1, o); s2 += __shfl_xor(s2, o); }
  __shared__ float r1[6], r2[6];
  int wv = threadIdx.x >> 6;
  if ((threadIdx.x & 63) == 0) { r1[wv] = s1; r2[wv] = s2; }
  __syncthreads();
  float S1 = 0.f, S2 = 0.f;
  #pragma unroll
  for (int i = 0; i < 6; i++) { S1 += r1[i]; S2 += r2[i]; }
  float mu = S1 * (1.f / 384.f);
  float var = S2 * (1.f / 384.f) - mu * mu;
  float rr = rsqrtf(var + 1e-5f);
  float yn = (v - mu) * rr * g[d] + be[d];
  float z = __bfloat162float(zbufB[(long)row * 384 + d]);
  float sg = z / (1.f + __expf(-z));
  yactb[(long)row * 384 + d] = __float2bfloat16(yn * sg);
}

extern "C" void kernel_launch(void* const* d_in, const int* in_sizes, int n_in,
                              void* d_out, int out_size, void* d_ws, size_t ws_size,
                              hipStream_t stream) {
  const float* input      = (const float*)d_in[0];
  const float* norm_g     = (const float*)d_in[1];
  const float* norm_b     = (const float*)d_in[2];
  const float* in_proj_w  = (const float*)d_in[3];
  const float* conv_w     = (const float*)d_in[4];
  const float* conv_b     = (const float*)d_in[5];
  const float* x_proj_w   = (const float*)d_in[6];
  const float* dt_w       = (const float*)d_in[7];
  const float* dt_b       = (const float*)d_in[8];
  const float* A_logs     = (const float*)d_in[9];
  const float* Ds         = (const float*)d_in[10];
  const float* out_norm_g = (const float*)d_in[11];
  const float* out_norm_b = (const float*)d_in[12];
  const float* out_proj_w = (const float*)d_in[13];
  float* out = (float*)d_out;

  // plane path total = 24,788,992 floats (~99 MB); atomic fallback = 21,643,264 (~87 MB)
  bool big = ws_size >= (size_t)24788992 * 4;

  float* ws = (float*)d_ws;
  long o = 0;
  __hip_bfloat16* xnb   = (__hip_bfloat16*)(ws + o); o += 786432;   // 8192x192 bf16
  __hip_bfloat16* xbufB = (__hip_bfloat16*)(ws + o); o += 1572864;  // 8192x384 bf16
  __hip_bfloat16* zbufB = (__hip_bfloat16*)(ws + o); o += 1572864;
  __hip_bfloat16* xcb   = (__hip_bfloat16*)(ws + o); o += 1572864;
  __hip_bfloat16* Wt1   = (__hip_bfloat16*)(ws + o); o += 73728;    // 768x192 bf16
  __hip_bfloat16* Wt2   = (__hip_bfloat16*)(ws + o); o += 36864;
  __hip_bfloat16* Wt3   = (__hip_bfloat16*)(ws + o); o += 36864;
  float* dtsS           = ws + o;                    o += 393216;   // (BK,p,12) pixel order
  float* BCs            = ws + o;                    o += 1048576;  // (BK,p,32): B|C interleaved
  __half* dpre          = (__half*)(ws + o);         o += 6291456;  // (BK,p,384) fp16 delta
  __half* EbH           = (__half*)(ws + o);         o += 3145728;  // (1024 segs, 6144) fp16
  float* Dend           = ws + o;                    o += 393216;   // (1024, 384) fp32
  __hip_bfloat16* ybufB = (__hip_bfloat16*)(ws + o);
  float* ysum           = ws + o;                    o += big ? 6291456 : 3145728;
  __hip_bfloat16* yactb = (__hip_bfloat16*)(ws + o); o += 1572864;

  k_lnpackw<<<dim3(3200), dim3(256), 0, stream>>>(input, norm_g, norm_b, xnb,
                                                  in_proj_w, x_proj_w, out_proj_w, Wt1, Wt2, Wt3);
  k_gemm_mfma<2, 128><<<dim3(6, 128), dim3(256), 0, stream>>>(xnb, Wt1, nullptr, nullptr, xbufB, zbufB,
                                                              nullptr, nullptr, 8192, 768, 192);
  k_conv<<<dim3(1024), dim3(384), 0, stream>>>(xbufB, conv_w, conv_b, xcb);
  k_gemm_mfma<3, 64><<<dim3(3, 128), dim3(256), 0, stream>>>(xcb, Wt2, nullptr, nullptr, nullptr, nullptr,
                                                             dtsS, BCs, 8192, 192, 384);
  k_dt<<<dim3(1024), dim3(384), 0, stream>>>(dtsS, dt_w, dt_b, dpre);
  k_scan0<<<dim3(1024), dim3(384), 0, stream>>>(dpre, BCs, xcb, A_logs, EbH, Dend);
  k_combine<<<dim3(3072), dim3(128), 0, stream>>>(EbH, Dend, A_logs);
  if (big) {
    k_scan1<0><<<dim3(1024), dim3(384), 0, stream>>>(dpre, BCs, xcb, A_logs, EbH, ybufB, nullptr);
    k_merge<1><<<dim3(8192), dim3(384), 0, stream>>>(ybufB, nullptr, xcb, zbufB, Ds,
                                                     out_norm_g, out_norm_b, yactb);
  } else {
    hipMemsetAsync(ysum, 0, (size_t)3145728 * 4, stream);
    k_scan1<1><<<dim3(1024), dim3(384), 0, stream>>>(dpre, BCs, xcb, A_logs, EbH, nullptr, ysum);
    k_merge<0><<<dim3(8192), dim3(384), 0, stream>>>(nullptr, ysum, xcb, zbufB, Ds,
                                                     out_norm_g, out_norm_b, yactb);
  }
  k_gemm_mfma<1, 64><<<dim3(3, 128), dim3(256), 0, stream>>>(yactb, Wt3, input, out, nullptr, nullptr,
                                                             nullptr, nullptr, 8192, 192, 384);
}

// Round 12
// 228.022 us; speedup vs baseline: 1.1256x; 1.1256x over previous
//
#include <hip/hip_runtime.h>
#include <hip/hip_bf16.h>
#include <hip/hip_fp16.h>

// VSSBlock: B=2 H=64 W=64 C=192 DM=384 N=16 R=12 K=4 L=4096
// R20: base = R18 (236.5us best; R19's register-burst scans reverted — VGPR 64 cost
//      occupancy, +20us). ONE change: k_dt fused into k_scan0 — scan0 computes
//      delta = softplus(dts@dt_w+dt_b) inline (broadcast dts rows) and WRITES the
//      fp16 dpre plane for scan1. Deletes one kernel + one dtsS read pass.

typedef __attribute__((ext_vector_type(8))) short short8;     // 8 bf16 = 4 VGPRs
typedef __attribute__((ext_vector_type(4))) float floatx4;    // fp32 accum frag

// ---------------- fused: LN (pre-norm, eps 1e-6) -> bf16  +  weight pack ----------------
__global__ __launch_bounds__(256) void k_lnpackw(const float* __restrict__ in,
                                                 const float* __restrict__ g,
                                                 const float* __restrict__ be,
                                                 __hip_bfloat16* __restrict__ out,
                                                 const float* __restrict__ ipw,
                                                 const float* __restrict__ xpw,
                                                 const float* __restrict__ opw,
                                                 __hip_bfloat16* __restrict__ Wt1,
                                                 __hip_bfloat16* __restrict__ Wt2,
                                                 __hip_bfloat16* __restrict__ Wt3) {
  int bid = blockIdx.x;
  if (bid < 2048) {                 // LayerNorm: 4 rows/block
    int row = bid * 4 + (threadIdx.x >> 6);
    int lane = threadIdx.x & 63;
    const float* x = in + (long)row * 192;
    float v0 = x[lane], v1 = x[lane + 64], v2 = x[lane + 128];
    float s = v0 + v1 + v2;
    float s2 = v0 * v0 + v1 * v1 + v2 * v2;
    #pragma unroll
    for (int o = 32; o > 0; o >>= 1) { s += __shfl_xor(s, o); s2 += __shfl_xor(s2, o); }
    float mu = s * (1.f / 192.f);
    float var = s2 * (1.f / 192.f) - mu * mu;
    float r = rsqrtf(var + 1e-6f);
    __hip_bfloat16* op = out + (long)row * 192;
    op[lane]       = __float2bfloat16((v0 - mu) * r * g[lane]       + be[lane]);
    op[lane + 64]  = __float2bfloat16((v1 - mu) * r * g[lane + 64]  + be[lane + 64]);
    op[lane + 128] = __float2bfloat16((v2 - mu) * r * g[lane + 128] + be[lane + 128]);
  } else {                          // weight pack
    int idx = (bid - 2048) * 256 + threadIdx.x;
    if (idx < 147456) {                       // Wt1[n][k] = ipw[k][n]
      int n = idx / 192, k = idx - n * 192;
      Wt1[idx] = __float2bfloat16(ipw[(long)k * 768 + n]);
    } else if (idx < 147456 + 73728) {        // Wt2[j][d]
      int t = idx - 147456;
      int j = t / 384;
      float v = (j < 176) ? xpw[t] : 0.f;
      Wt2[t] = __float2bfloat16(v);
    } else if (idx < 147456 + 73728 + 73728) {// Wt3[n][k] = opw[k][n]
      int t = idx - 147456 - 73728;
      int n = t / 384, k = t - n * 384;
      Wt3[t] = __float2bfloat16(opw[(long)k * 192 + n]);
    }
  }
}

// direction map (involutions): pixel p <-> scan position l
__device__ __forceinline__ int inv_dir(int k, int p) {
  int pt = ((p & 63) << 6) | (p >> 6);
  if (k == 0) return p;
  if (k == 1) return pt;
  if (k == 2) return 4095 - p;
  return 4095 - pt;
}
__device__ __forceinline__ int dir_pix(int k, int l) { return inv_dir(k, l); }

// ---------------- bf16 MFMA GEMM: 64xTN tile, BK=64, XOR-swizzled LDS ----------------
template <int EPI, int TN>
__global__ __launch_bounds__(256) void k_gemm_mfma(const __hip_bfloat16* __restrict__ A,
                                                   const __hip_bfloat16* __restrict__ Bt,
                                                   const float* __restrict__ Res,
                                                   float* __restrict__ Co,
                                                   __hip_bfloat16* __restrict__ CoB,
                                                   __hip_bfloat16* __restrict__ Co2B,
                                                   float* __restrict__ dtsS,
                                                   float* __restrict__ BCs,
                                                   int M, int N, int Kk) {
  constexpr int NI = TN / 32;
  __shared__ __align__(16) short As[64 * 64];
  __shared__ __align__(16) short Bs[TN * 64];
  int tid = threadIdx.x;
  int wave = tid >> 6, lane = tid & 63;
  int mlane = lane & 15, quad = lane >> 4;
  int row0 = blockIdx.y * 64, col0 = blockIdx.x * TN;
  int wr = wave & 1, wc = wave >> 1;
  floatx4 acc[2][NI];
  #pragma unroll
  for (int mi = 0; mi < 2; mi++)
    #pragma unroll
    for (int ni = 0; ni < NI; ni++) acc[mi][ni] = (floatx4){0.f, 0.f, 0.f, 0.f};

  for (int k0 = 0; k0 < Kk; k0 += 64) {
    #pragma unroll
    for (int c = tid; c < 512; c += 256) {
      int r = c >> 3, j = c & 7;
      *(float4*)&As[r * 64 + ((j ^ (r & 7)) << 3)] =
          *(const float4*)&A[(long)(row0 + r) * Kk + k0 + j * 8];
    }
    #pragma unroll
    for (int c = tid; c < TN * 8; c += 256) {
      int r = c >> 3, j = c & 7;
      *(float4*)&Bs[r * 64 + ((j ^ (r & 7)) << 3)] =
          *(const float4*)&Bt[(long)(col0 + r) * Kk + k0 + j * 8];
    }
    __syncthreads();
    short8 af[2][2], bf[NI][2];
    #pragma unroll
    for (int mi = 0; mi < 2; mi++) {
      int r = wr * 32 + mi * 16 + mlane;
      #pragma unroll
      for (int kk = 0; kk < 2; kk++) {
        int jx = (kk * 4 + quad) ^ (r & 7);
        af[mi][kk] = *(const short8*)&As[r * 64 + jx * 8];
      }
    }
    #pragma unroll
    for (int ni = 0; ni < NI; ni++) {
      int rn = wc * (TN / 2) + ni * 16 + mlane;
      #pragma unroll
      for (int kk = 0; kk < 2; kk++) {
        int jx = (kk * 4 + quad) ^ (rn & 7);
        bf[ni][kk] = *(const short8*)&Bs[rn * 64 + jx * 8];
      }
    }
    #pragma unroll
    for (int kk = 0; kk < 2; kk++)
      #pragma unroll
      for (int mi = 0; mi < 2; mi++)
        #pragma unroll
        for (int ni = 0; ni < NI; ni++)
          acc[mi][ni] = __builtin_amdgcn_mfma_f32_16x16x32_bf16(af[mi][kk], bf[ni][kk],
                                                                acc[mi][ni], 0, 0, 0);
    __syncthreads();
  }
  // C/D layout: col=lane&15, row=quad*4+reg  [m89-verified]
  #pragma unroll
  for (int mi = 0; mi < 2; mi++) {
    #pragma unroll
    for (int ni = 0; ni < NI; ni++) {
      int cc = col0 + wc * (TN / 2) + ni * 16 + mlane;
      #pragma unroll
      for (int i = 0; i < 4; i++) {
        int rr = row0 + wr * 32 + mi * 16 + quad * 4 + i;
        float v = acc[mi][ni][i];
        if (EPI == 1) {
          Co[(long)rr * N + cc] = v + Res[(long)rr * N + cc];
        } else if (EPI == 2) {
          if (cc < 384) CoB[(long)rr * 384 + cc] = __float2bfloat16(v);
          else          Co2B[(long)rr * 384 + (cc - 384)] = __float2bfloat16(v);
        } else {  // EPI == 3: pixel-order split; B at 0..15, C at 16..31 of BCs row
          if (cc < 176) {
            int k4 = (cc >= 132) ? 3 : (cc >= 88) ? 2 : (cc >= 44) ? 1 : 0;
            int c = cc - k4 * 44;
            int b = rr >> 12, p = rr & 4095;
            long lbase = ((long)((b << 2) + k4) << 12) + p;   // pixel order
            if (c < 12) dtsS[lbase * 12 + c] = v;
            else        BCs[lbase * 32 + (c - 12)] = v;
          }
        }
      }
    }
  }
}

// ---------------- depthwise 3x3 conv + bias + SiLU; 2x4 pixels/block; bf16 in/out ----------------
__global__ __launch_bounds__(384) void k_conv(const __hip_bfloat16* __restrict__ xbufB,
                                              const float* __restrict__ cw,
                                              const float* __restrict__ cb,
                                              __hip_bfloat16* __restrict__ xcb) {
  int blk = blockIdx.x;            // 1024: b(2) x hgroup(32) x wgroup(16)
  int wg = blk & 15, hg = (blk >> 4) & 31, b = blk >> 9;
  int h0 = hg * 2, w0 = wg * 4;
  int d = threadIdx.x;
  float wt[9];
  const float* wp = cw + d * 9;
  #pragma unroll
  for (int i = 0; i < 9; i++) wt[i] = wp[i];
  float bias = cb[d];
  float v[4][6];
  #pragma unroll
  for (int r = 0; r < 4; r++) {
    int hh = h0 + r - 1;
    bool rok = (hh >= 0) && (hh < 64);
    #pragma unroll
    for (int c = 0; c < 6; c++) {
      int ww = w0 + c - 1;
      bool ok = rok && (ww >= 0) && (ww < 64);
      v[r][c] = ok ? __bfloat162float(xbufB[((long)(b << 12) + (hh << 6) + ww) * 384 + d]) : 0.f;
    }
  }
  #pragma unroll
  for (int i = 0; i < 2; i++) {
    #pragma unroll
    for (int j = 0; j < 4; j++) {
      float acc = bias;
      #pragma unroll
      for (int r = 0; r < 3; r++)
        #pragma unroll
        for (int c = 0; c < 3; c++)
          acc += v[i + r][j + c] * wt[r * 3 + c];
      float sg = 1.f / (1.f + __expf(-acc));
      xcb[((long)(b << 12) + ((h0 + i) << 6) + (w0 + j)) * 384 + d] = __float2bfloat16(acc * sg);
    }
  }
}

// powers: pws[n] = r^(n+1), log-depth pairing
__device__ __forceinline__ void pow16(float r, float* pws) {
  pws[0] = r;
  #pragma unroll
  for (int n = 1; n < 16; n++) {
    int m = n + 1, c = (m + 1) / 2, f = m - c;
    pws[n] = pws[c - 1] * pws[f - 1];
  }
}

// ---------------- scan pass 0 (+dt fused): 128 segments x 32 steps ----------------
// Computes delta inline from dtsS (broadcast rows) + dt_w/dt_b, writes fp16 dpre for
// scan1, accumulates E[16] (stored fp16) + scalar cumDelta.
__global__ __launch_bounds__(384) void k_scan0(
    const float* __restrict__ dtsS, const float* __restrict__ BCs,
    const __hip_bfloat16* __restrict__ xcb,
    const float* __restrict__ A_logs, const float* __restrict__ dt_w,
    const float* __restrict__ dt_b,
    __half* __restrict__ dpre, __half* __restrict__ EbH, float* __restrict__ Dend) {
  int bid = blockIdx.x;
  int s = bid & 127, bk = bid >> 7;
  int k = bk & 3, b = bk >> 2;
  int d = threadIdx.x;
  float w[12];
  const float* dwp = dt_w + ((long)(k * 384) + d) * 12;
  #pragma unroll
  for (int r = 0; r < 12; r++) w[r] = dwp[r];
  float db = dt_b[k * 384 + d];
  const float* al = A_logs + ((long)(k * 384) + d) * 16;
  bool pw = true;
  float av[16];
  #pragma unroll
  for (int n = 0; n < 16; n++) {
    float a = __expf(al[n]);
    av[n] = -a;
    pw = pw && (fabsf(a - (float)(n + 1)) < 1e-3f);
  }
  float h[16];
  #pragma unroll
  for (int n = 0; n < 16; n++) h[n] = 0.f;
  float cum = 0.f;
  long bpk = (long)bk << 12;
  long bpix = (long)(b << 12);

  if (pw) {
    #pragma unroll 4
    for (int t = 0; t < 32; t++) {
      int p = dir_pix(k, s * 32 + t);
      const float4* dq = (const float4*)(dtsS + (bpk + p) * 12);
      float4 q0 = dq[0], q1 = dq[1], q2 = dq[2];
      float x = db + q0.x * w[0] + q0.y * w[1] + q0.z * w[2] + q0.w * w[3]
                   + q1.x * w[4] + q1.y * w[5] + q1.z * w[6] + q1.w * w[7]
                   + q2.x * w[8] + q2.y * w[9] + q2.z * w[10] + q2.w * w[11];
      float e = __expf(x);
      float delta = (x > 15.f) ? x : __logf(1.f + e);
      dpre[(bpk + p) * 384 + d] = __float2half(delta);
      float u = __bfloat162float(xcb[(bpix + p) * 384 + d]);
      cum += delta;
      float du = delta * u;
      float rr = __expf(-delta);
      float pws[16]; pow16(rr, pws);
      const float4* Bq = (const float4*)(BCs + (bpk + p) * 32);
      float4 b0 = Bq[0], b1 = Bq[1], b2 = Bq[2], b3 = Bq[3];
      float Bl[16] = {b0.x, b0.y, b0.z, b0.w, b1.x, b1.y, b1.z, b1.w,
                      b2.x, b2.y, b2.z, b2.w, b3.x, b3.y, b3.z, b3.w};
      #pragma unroll
      for (int n = 0; n < 16; n++) h[n] = pws[n] * h[n] + du * Bl[n];
    }
  } else {
    for (int t = 0; t < 32; t++) {
      int p = dir_pix(k, s * 32 + t);
      const float4* dq = (const float4*)(dtsS + (bpk + p) * 12);
      float4 q0 = dq[0], q1 = dq[1], q2 = dq[2];
      float x = db + q0.x * w[0] + q0.y * w[1] + q0.z * w[2] + q0.w * w[3]
                   + q1.x * w[4] + q1.y * w[5] + q1.z * w[6] + q1.w * w[7]
                   + q2.x * w[8] + q2.y * w[9] + q2.z * w[10] + q2.w * w[11];
      float e = __expf(x);
      float delta = (x > 15.f) ? x : __logf(1.f + e);
      dpre[(bpk + p) * 384 + d] = __float2half(delta);
      float u = __bfloat162float(xcb[(bpix + p) * 384 + d]);
      cum += delta;
      float du = delta * u;
      const float4* Bq = (const float4*)(BCs + (bpk + p) * 32);
      float4 b0 = Bq[0], b1 = Bq[1], b2 = Bq[2], b3 = Bq[3];
      float Bl[16] = {b0.x, b0.y, b0.z, b0.w, b1.x, b1.y, b1.z, b1.w,
                      b2.x, b2.y, b2.z, b2.w, b3.x, b3.y, b3.z, b3.w};
      #pragma unroll
      for (int n = 0; n < 16; n++) {
        float dA = __expf(delta * av[n]);
        h[n] = dA * h[n] + du * Bl[n];
      }
    }
  }
  long g = (long)bk * 128 + s;
  __half2* Ep = (__half2*)(EbH + g * 6144 + (long)d * 16);
  #pragma unroll
  for (int n = 0; n < 8; n++) {
    __half2 hv;
    hv.x = __float2half(h[2 * n]);
    hv.y = __float2half(h[2 * n + 1]);
    Ep[n] = hv;
  }
  Dend[g * 384 + d] = cum;
}

// ---------------- combine: Kogge-Stone over 128 segments; fp16 I/O, fp32 internal ----------------
__global__ __launch_bounds__(128) void k_combine(__half* __restrict__ EbH,
                                                 const float* __restrict__ Dend,
                                                 const float* __restrict__ A_logs) {
  int bid = blockIdx.x;            // bk*384 + d, 3072 blocks
  int bk = bid / 384;
  int d = bid - bk * 384;
  int k = bk & 3;
  int s = threadIdx.x;             // segment 0..127
  const float* al = A_logs + ((long)(k * 384) + d) * 16;
  bool pw = true;
  float av[16];
  #pragma unroll
  for (int n = 0; n < 16; n++) {
    float a = __expf(al[n]);
    av[n] = -a;
    pw = pw && (fabsf(a - (float)(n + 1)) < 1e-3f);
  }

  long ebase = ((long)bk * 128 + s) * 6144 + (long)d * 16;
  float e[16];
  {
    const __half2* Ein = (const __half2*)(EbH + ebase);
    #pragma unroll
    for (int n = 0; n < 8; n++) {
      __half2 hv = Ein[n];
      e[2 * n]     = __half2float(hv.x);
      e[2 * n + 1] = __half2float(hv.y);
    }
  }
  float sig = Dend[((long)bk * 128 + s) * 384 + d];

  __shared__ float sE[128][17];    // [s][0]=sigma, [s][1..16]=e
  sE[s][0] = sig;
  #pragma unroll
  for (int n = 0; n < 16; n++) sE[s][1 + n] = e[n];
  __syncthreads();

  for (int o = 1; o < 128; o <<= 1) {
    float ps = 0.f, pe[16];
    bool act = (s >= o);
    if (act) {
      ps = sE[s - o][0];
      #pragma unroll
      for (int n = 0; n < 16; n++) pe[n] = sE[s - o][1 + n];
    }
    __syncthreads();
    if (act) {
      if (pw) {
        float rc = __expf(-sig);
        float pwr[16]; pow16(rc, pwr);      // pwr[n] = exp(av[n]*sig), av[n]=-(n+1)
        #pragma unroll
        for (int n = 0; n < 16; n++) e[n] += pwr[n] * pe[n];
      } else {
        #pragma unroll
        for (int n = 0; n < 16; n++) e[n] += __expf(av[n] * sig) * pe[n];
      }
      sig += ps;
      sE[s][0] = sig;
      #pragma unroll
      for (int n = 0; n < 16; n++) sE[s][1 + n] = e[n];
    }
    __syncthreads();
  }

  float ho[16];
  if (s == 0) {
    #pragma unroll
    for (int n = 0; n < 16; n++) ho[n] = 0.f;
  } else {
    #pragma unroll
    for (int n = 0; n < 16; n++) ho[n] = sE[s - 1][1 + n];
  }
  __half2* Eo = (__half2*)(EbH + ebase);
  #pragma unroll
  for (int n = 0; n < 8; n++) {
    __half2 hv;
    hv.x = __float2half(ho[2 * n]);
    hv.y = __float2half(ho[2 * n + 1]);
    Eo[n] = hv;
  }
}

// ---------------- scan pass 1: full recurrence from h_in (fp16 in EbH) ----------------
// ATOMIC=0: store y bf16 into per-direction plane ybufB. ATOMIC=1: fp32 atomicAdd ysum.
template <int ATOMIC>
__global__ __launch_bounds__(384) void k_scan1(
    const __half* __restrict__ dpre, const float* __restrict__ BCs,
    const __hip_bfloat16* __restrict__ xcb,
    const float* __restrict__ A_logs, const __half* __restrict__ EbH,
    __hip_bfloat16* __restrict__ ybufB, float* __restrict__ ysum) {
  int bid = blockIdx.x;
  int s = bid & 127, bk = bid >> 7;
  int k = bk & 3, b = bk >> 2;
  int d = threadIdx.x;
  const float* al = A_logs + ((long)(k * 384) + d) * 16;
  bool pw = true;
  float av[16];
  #pragma unroll
  for (int n = 0; n < 16; n++) {
    float a = __expf(al[n]);
    av[n] = -a;
    pw = pw && (fabsf(a - (float)(n + 1)) < 1e-3f);
  }
  float h[16];
  {
    const __half2* hp = (const __half2*)(EbH + ((long)bk * 128 + s) * 6144 + (long)d * 16);
    #pragma unroll
    for (int n = 0; n < 8; n++) {
      __half2 hv = hp[n];
      h[2 * n]     = __half2float(hv.x);
      h[2 * n + 1] = __half2float(hv.y);
    }
  }
  long bpk = (long)bk << 12;
  long bpix = (long)(b << 12);

  if (pw) {
    #pragma unroll 4
    for (int t = 0; t < 32; t++) {
      int p = dir_pix(k, s * 32 + t);
      float delta = __half2float(dpre[(bpk + p) * 384 + d]);
      float u = __bfloat162float(xcb[(bpix + p) * 384 + d]);
      float du = delta * u;
      float rr = __expf(-delta);
      float pws[16]; pow16(rr, pws);
      const float4* Bq = (const float4*)(BCs + (bpk + p) * 32);
      float4 b0 = Bq[0], b1 = Bq[1], b2 = Bq[2], b3 = Bq[3];
      float Bl[16] = {b0.x, b0.y, b0.z, b0.w, b1.x, b1.y, b1.z, b1.w,
                      b2.x, b2.y, b2.z, b2.w, b3.x, b3.y, b3.z, b3.w};
      const float4* Cq = Bq + 4;
      float4 c0 = Cq[0], c1 = Cq[1], c2 = Cq[2], c3 = Cq[3];
      float Cl[16] = {c0.x, c0.y, c0.z, c0.w, c1.x, c1.y, c1.z, c1.w,
                      c2.x, c2.y, c2.z, c2.w, c3.x, c3.y, c3.z, c3.w};
      float y = 0.f;
      #pragma unroll
      for (int n = 0; n < 16; n++) { h[n] = pws[n] * h[n] + du * Bl[n]; y += h[n] * Cl[n]; }
      if (ATOMIC) atomicAdd(&ysum[(bpix + p) * 384 + d], y);
      else        ybufB[(bpk + p) * 384 + d] = __float2bfloat16(y);
    }
  } else {
    for (int t = 0; t < 32; t++) {
      int p = dir_pix(k, s * 32 + t);
      float delta = __half2float(dpre[(bpk + p) * 384 + d]);
      float u = __bfloat162float(xcb[(bpix + p) * 384 + d]);
      float du = delta * u;
      const float4* Bq = (const float4*)(BCs + (bpk + p) * 32);
      float4 b0 = Bq[0], b1 = Bq[1], b2 = Bq[2], b3 = Bq[3];
      float Bl[16] = {b0.x, b0.y, b0.z, b0.w, b1.x, b1.y, b1.z, b1.w,
                      b2.x, b2.y, b2.z, b2.w, b3.x, b3.y, b3.z, b3.w};
      const float4* Cq = Bq + 4;
      float4 c0 = Cq[0], c1 = Cq[1], c2 = Cq[2], c3 = Cq[3];
      float Cl[16] = {c0.x, c0.y, c0.z, c0.w, c1.x, c1.y, c1.z, c1.w,
                      c2.x, c2.y, c2.z, c2.w, c3.x, c3.y, c3.z, c3.w};
      float y = 0.f;
      #pragma unroll
      for (int n = 0; n < 16; n++) {
        float dA = __expf(delta * av[n]);
        h[n] = dA * h[n] + du * Bl[n];
        y += h[n] * Cl[n];
      }
      if (ATOMIC) atomicAdd(&ysum[(bpix + p) * 384 + d], y);
      else        ybufB[(bpk + p) * 384 + d] = __float2bfloat16(y);
    }
  }
}

// ---------------- merge: y + D-skip(bf16 xcb) + out-LN + silu(z bf16) -> bf16 ----------------
template <int GATHER>
__global__ __launch_bounds__(384) void k_merge(const __hip_bfloat16* __restrict__ yinB,
                                               const float* __restrict__ yinF,
                                               const __hip_bfloat16* __restrict__ xcb,
                                               const __hip_bfloat16* __restrict__ zbufB,
                                               const float* __restrict__ Ds,
                                               const float* __restrict__ g,
                                               const float* __restrict__ be,
                                               __hip_bfloat16* __restrict__ yactb) {
  int row = blockIdx.x;
  int d = threadIdx.x;
  float v;
  if (GATHER) {
    int b = row >> 12, p = row & 4095;
    long base = ((long)(b << 2) << 12) + p;  // plane (b*4+k)*4096 + p
    v = __bfloat162float(yinB[base * 384 + d])
      + __bfloat162float(yinB[(base + 4096) * 384 + d])
      + __bfloat162float(yinB[(base + 8192) * 384 + d])
      + __bfloat162float(yinB[(base + 12288) * 384 + d]);
  } else {
    v = yinF[(long)row * 384 + d];
  }
  float sd = Ds[d] + Ds[384 + d] + Ds[768 + d] + Ds[1152 + d];
  v += __bfloat162float(xcb[(long)row * 384 + d]) * sd;
  float s1 = v, s2 = v * v;
  #pragma unroll
  for (int o = 32; o > 0; o >>= 1) { s1 += __shfl_xor(s1, o); s2 += __shfl_xor(s2, o); }
  __shared__ float r1[6], r2[6];
  int wv = threadIdx.x >> 6;
  if ((threadIdx.x & 63) == 0) { r1[wv] = s1; r2[wv] = s2; }
  __syncthreads();
  float S1 = 0.f, S2 = 0.f;
  #pragma unroll
  for (int i = 0; i < 6; i++) { S1 += r1[i]; S2 += r2[i]; }
  float mu = S1 * (1.f / 384.f);
  float var = S2 * (1.f / 384.f) - mu * mu;
  float rr = rsqrtf(var + 1e-5f);
  float yn = (v - mu) * rr * g[d] + be[d];
  float z = __bfloat162float(zbufB[(long)row * 384 + d]);
  float sg = z / (1.f + __expf(-z));
  yactb[(long)row * 384 + d] = __float2bfloat16(yn * sg);
}

extern "C" void kernel_launch(void* const* d_in, const int* in_sizes, int n_in,
                              void* d_out, int out_size, void* d_ws, size_t ws_size,
                              hipStream_t stream) {
  const float* input      = (const float*)d_in[0];
  const float* norm_g     = (const float*)d_in[1];
  const float* norm_b     = (const float*)d_in[2];
  const float* in_proj_w  = (const float*)d_in[3];
  const float* conv_w     = (const float*)d_in[4];
  const float* conv_b     = (const float*)d_in[5];
  const float* x_proj_w   = (const float*)d_in[6];
  const float* dt_w       = (const float*)d_in[7];
  const float* dt_b       = (const float*)d_in[8];
  const float* A_logs     = (const float*)d_in[9];
  const float* Ds         = (const float*)d_in[10];
  const float* out_norm_g = (const float*)d_in[11];
  const float* out_norm_b = (const float*)d_in[12];
  const float* out_proj_w = (const float*)d_in[13];
  float* out = (float*)d_out;

  // plane path total = 24,788,992 floats (~99 MB); atomic fallback = 21,643,264 (~87 MB)
  bool big = ws_size >= (size_t)24788992 * 4;

  float* ws = (float*)d_ws;
  long o = 0;
  __hip_bfloat16* xnb   = (__hip_bfloat16*)(ws + o); o += 786432;   // 8192x192 bf16
  __hip_bfloat16* xbufB = (__hip_bfloat16*)(ws + o); o += 1572864;  // 8192x384 bf16
  __hip_bfloat16* zbufB = (__hip_bfloat16*)(ws + o); o += 1572864;
  __hip_bfloat16* xcb   = (__hip_bfloat16*)(ws + o); o += 1572864;
  __hip_bfloat16* Wt1   = (__hip_bfloat16*)(ws + o); o += 73728;    // 768x192 bf16
  __hip_bfloat16* Wt2   = (__hip_bfloat16*)(ws + o); o += 36864;
  __hip_bfloat16* Wt3   = (__hip_bfloat16*)(ws + o); o += 36864;
  float* dtsS           = ws + o;                    o += 393216;   // (BK,p,12) pixel order
  float* BCs            = ws + o;                    o += 1048576;  // (BK,p,32): B|C interleaved
  __half* dpre          = (__half*)(ws + o);         o += 6291456;  // (BK,p,384) fp16 delta
  __half* EbH           = (__half*)(ws + o);         o += 3145728;  // (1024 segs, 6144) fp16
  float* Dend           = ws + o;                    o += 393216;   // (1024, 384) fp32
  __hip_bfloat16* ybufB = (__hip_bfloat16*)(ws + o);
  float* ysum           = ws + o;                    o += big ? 6291456 : 3145728;
  __hip_bfloat16* yactb = (__hip_bfloat16*)(ws + o); o += 1572864;

  k_lnpackw<<<dim3(3200), dim3(256), 0, stream>>>(input, norm_g, norm_b, xnb,
                                                  in_proj_w, x_proj_w, out_proj_w, Wt1, Wt2, Wt3);
  k_gemm_mfma<2, 128><<<dim3(6, 128), dim3(256), 0, stream>>>(xnb, Wt1, nullptr, nullptr, xbufB, zbufB,
                                                              nullptr, nullptr, 8192, 768, 192);
  k_conv<<<dim3(1024), dim3(384), 0, stream>>>(xbufB, conv_w, conv_b, xcb);
  k_gemm_mfma<3, 64><<<dim3(3, 128), dim3(256), 0, stream>>>(xcb, Wt2, nullptr, nullptr, nullptr, nullptr,
                                                             dtsS, BCs, 8192, 192, 384);
  k_scan0<<<dim3(1024), dim3(384), 0, stream>>>(dtsS, BCs, xcb, A_logs, dt_w, dt_b,
                                                dpre, EbH, Dend);
  k_combine<<<dim3(3072), dim3(128), 0, stream>>>(EbH, Dend, A_logs);
  if (big) {
    k_scan1<0><<<dim3(1024), dim3(384), 0, stream>>>(dpre, BCs, xcb, A_logs, EbH, ybufB, nullptr);
    k_merge<1><<<dim3(8192), dim3(384), 0, stream>>>(ybufB, nullptr, xcb, zbufB, Ds,
                                                     out_norm_g, out_norm_b, yactb);
  } else {
    hipMemsetAsync(ysum, 0, (size_t)3145728 * 4, stream);
    k_scan1<1><<<dim3(1024), dim3(384), 0, stream>>>(dpre, BCs, xcb, A_logs, EbH, nullptr, ysum);
    k_merge<0><<<dim3(8192), dim3(384), 0, stream>>>(nullptr, ysum, xcb, zbufB, Ds,
                                                     out_norm_g, out_norm_b, yactb);
  }
  k_gemm_mfma<1, 64><<<dim3(3, 128), dim3(256), 0, stream>>>(yactb, Wt3, input, out, nullptr, nullptr,
                                                             nullptr, nullptr, 8192, 192, 384);
}

// Round 14
// 221.523 us; speedup vs baseline: 1.1587x; 1.0293x over previous
//
#include <hip/hip_runtime.h>
#include <hip/hip_bf16.h>
#include <hip/hip_fp16.h>

// VSSBlock: B=2 H=64 W=64 C=192 DM=384 N=16 R=12 K=4 L=4096
// R22 = R21 resubmitted verbatim (R13's bench was an infra failure, kernel never ran).
// Base = R20 (228.0us best). Three issue-count cuts, scans untouched:
//      (1) k_conv d-paired (192 thr x 2 ch): ushort2 loads halve VMEM issues;
//      (2) k_merge d-paired likewise (3-wave LN reduction);
//      (3) gemm<2> TN=192 (A-panel re-reads 6->4 col-blocks).

typedef __attribute__((ext_vector_type(8))) short short8;     // 8 bf16 = 4 VGPRs
typedef __attribute__((ext_vector_type(4))) float floatx4;    // fp32 accum frag

// ---------------- fused: LN (pre-norm, eps 1e-6) -> bf16  +  weight pack ----------------
__global__ __launch_bounds__(256) void k_lnpackw(const float* __restrict__ in,
                                                 const float* __restrict__ g,
                                                 const float* __restrict__ be,
                                                 __hip_bfloat16* __restrict__ out,
                                                 const float* __restrict__ ipw,
                                                 const float* __restrict__ xpw,
                                                 const float* __restrict__ opw,
                                                 __hip_bfloat16* __restrict__ Wt1,
                                                 __hip_bfloat16* __restrict__ Wt2,
                                                 __hip_bfloat16* __restrict__ Wt3) {
  int bid = blockIdx.x;
  if (bid < 2048) {                 // LayerNorm: 4 rows/block
    int row = bid * 4 + (threadIdx.x >> 6);
    int lane = threadIdx.x & 63;
    const float* x = in + (long)row * 192;
    float v0 = x[lane], v1 = x[lane + 64], v2 = x[lane + 128];
    float s = v0 + v1 + v2;
    float s2 = v0 * v0 + v1 * v1 + v2 * v2;
    #pragma unroll
    for (int o = 32; o > 0; o >>= 1) { s += __shfl_xor(s, o); s2 += __shfl_xor(s2, o); }
    float mu = s * (1.f / 192.f);
    float var = s2 * (1.f / 192.f) - mu * mu;
    float r = rsqrtf(var + 1e-6f);
    __hip_bfloat16* op = out + (long)row * 192;
    op[lane]       = __float2bfloat16((v0 - mu) * r * g[lane]       + be[lane]);
    op[lane + 64]  = __float2bfloat16((v1 - mu) * r * g[lane + 64]  + be[lane + 64]);
    op[lane + 128] = __float2bfloat16((v2 - mu) * r * g[lane + 128] + be[lane + 128]);
  } else {                          // weight pack
    int idx = (bid - 2048) * 256 + threadIdx.x;
    if (idx < 147456) {                       // Wt1[n][k] = ipw[k][n]
      int n = idx / 192, k = idx - n * 192;
      Wt1[idx] = __float2bfloat16(ipw[(long)k * 768 + n]);
    } else if (idx < 147456 + 73728) {        // Wt2[j][d]
      int t = idx - 147456;
      int j = t / 384;
      float v = (j < 176) ? xpw[t] : 0.f;
      Wt2[t] = __float2bfloat16(v);
    } else if (idx < 147456 + 73728 + 73728) {// Wt3[n][k] = opw[k][n]
      int t = idx - 147456 - 73728;
      int n = t / 384, k = t - n * 384;
      Wt3[t] = __float2bfloat16(opw[(long)k * 192 + n]);
    }
  }
}

// direction map (involutions): pixel p <-> scan position l
__device__ __forceinline__ int inv_dir(int k, int p) {
  int pt = ((p & 63) << 6) | (p >> 6);
  if (k == 0) return p;
  if (k == 1) return pt;
  if (k == 2) return 4095 - p;
  return 4095 - pt;
}
__device__ __forceinline__ int dir_pix(int k, int l) { return inv_dir(k, l); }

// ---------------- bf16 MFMA GEMM: 64xTN tile, BK=64, XOR-swizzled LDS ----------------
template <int EPI, int TN>
__global__ __launch_bounds__(256) void k_gemm_mfma(const __hip_bfloat16* __restrict__ A,
                                                   const __hip_bfloat16* __restrict__ Bt,
                                                   const float* __restrict__ Res,
                                                   float* __restrict__ Co,
                                                   __hip_bfloat16* __restrict__ CoB,
                                                   __hip_bfloat16* __restrict__ Co2B,
                                                   float* __restrict__ dtsS,
                                                   float* __restrict__ BCs,
                                                   int M, int N, int Kk) {
  constexpr int NI = TN / 32;
  __shared__ __align__(16) short As[64 * 64];
  __shared__ __align__(16) short Bs[TN * 64];
  int tid = threadIdx.x;
  int wave = tid >> 6, lane = tid & 63;
  int mlane = lane & 15, quad = lane >> 4;
  int row0 = blockIdx.y * 64, col0 = blockIdx.x * TN;
  int wr = wave & 1, wc = wave >> 1;
  floatx4 acc[2][NI];
  #pragma unroll
  for (int mi = 0; mi < 2; mi++)
    #pragma unroll
    for (int ni = 0; ni < NI; ni++) acc[mi][ni] = (floatx4){0.f, 0.f, 0.f, 0.f};

  for (int k0 = 0; k0 < Kk; k0 += 64) {
    #pragma unroll
    for (int c = tid; c < 512; c += 256) {
      int r = c >> 3, j = c & 7;
      *(float4*)&As[r * 64 + ((j ^ (r & 7)) << 3)] =
          *(const float4*)&A[(long)(row0 + r) * Kk + k0 + j * 8];
    }
    #pragma unroll
    for (int c = tid; c < TN * 8; c += 256) {
      int r = c >> 3, j = c & 7;
      *(float4*)&Bs[r * 64 + ((j ^ (r & 7)) << 3)] =
          *(const float4*)&Bt[(long)(col0 + r) * Kk + k0 + j * 8];
    }
    __syncthreads();
    short8 af[2][2], bf[NI][2];
    #pragma unroll
    for (int mi = 0; mi < 2; mi++) {
      int r = wr * 32 + mi * 16 + mlane;
      #pragma unroll
      for (int kk = 0; kk < 2; kk++) {
        int jx = (kk * 4 + quad) ^ (r & 7);
        af[mi][kk] = *(const short8*)&As[r * 64 + jx * 8];
      }
    }
    #pragma unroll
    for (int ni = 0; ni < NI; ni++) {
      int rn = wc * (TN / 2) + ni * 16 + mlane;
      #pragma unroll
      for (int kk = 0; kk < 2; kk++) {
        int jx = (kk * 4 + quad) ^ (rn & 7);
        bf[ni][kk] = *(const short8*)&Bs[rn * 64 + jx * 8];
      }
    }
    #pragma unroll
    for (int kk = 0; kk < 2; kk++)
      #pragma unroll
      for (int mi = 0; mi < 2; mi++)
        #pragma unroll
        for (int ni = 0; ni < NI; ni++)
          acc[mi][ni] = __builtin_amdgcn_mfma_f32_16x16x32_bf16(af[mi][kk], bf[ni][kk],
                                                                acc[mi][ni], 0, 0, 0);
    __syncthreads();
  }
  // C/D layout: col=lane&15, row=quad*4+reg  [m89-verified]
  #pragma unroll
  for (int mi = 0; mi < 2; mi++) {
    #pragma unroll
    for (int ni = 0; ni < NI; ni++) {
      int cc = col0 + wc * (TN / 2) + ni * 16 + mlane;
      #pragma unroll
      for (int i = 0; i < 4; i++) {
        int rr = row0 + wr * 32 + mi * 16 + quad * 4 + i;
        float v = acc[mi][ni][i];
        if (EPI == 1) {
          Co[(long)rr * N + cc] = v + Res[(long)rr * N + cc];
        } else if (EPI == 2) {
          if (cc < 384) CoB[(long)rr * 384 + cc] = __float2bfloat16(v);
          else          Co2B[(long)rr * 384 + (cc - 384)] = __float2bfloat16(v);
        } else {  // EPI == 3: pixel-order split; B at 0..15, C at 16..31 of BCs row
          if (cc < 176) {
            int k4 = (cc >= 132) ? 3 : (cc >= 88) ? 2 : (cc >= 44) ? 1 : 0;
            int c = cc - k4 * 44;
            int b = rr >> 12, p = rr & 4095;
            long lbase = ((long)((b << 2) + k4) << 12) + p;   // pixel order
            if (c < 12) dtsS[lbase * 12 + c] = v;
            else        BCs[lbase * 32 + (c - 12)] = v;
          }
        }
      }
    }
  }
}

// ---------------- depthwise 3x3 conv + bias + SiLU; 2x4 pixels, d-paired ----------------
__global__ __launch_bounds__(192) void k_conv(const __hip_bfloat16* __restrict__ xbufB,
                                              const float* __restrict__ cw,
                                              const float* __restrict__ cb,
                                              __hip_bfloat16* __restrict__ xcb) {
  int blk = blockIdx.x;            // 1024: b(2) x hgroup(32) x wgroup(16)
  int wg = blk & 15, hg = (blk >> 4) & 31, b = blk >> 9;
  int h0 = hg * 2, w0 = wg * 4;
  int d0 = threadIdx.x * 2;        // channel pair d0, d0+1
  float wt0[9], wt1[9];
  #pragma unroll
  for (int i = 0; i < 9; i++) { wt0[i] = cw[(long)d0 * 9 + i]; wt1[i] = cw[(long)(d0 + 1) * 9 + i]; }
  float2 bias = *(const float2*)&cb[d0];
  float v0[4][6], v1[4][6];
  #pragma unroll
  for (int r = 0; r < 4; r++) {
    int hh = h0 + r - 1;
    bool rok = (hh >= 0) && (hh < 64);
    #pragma unroll
    for (int c = 0; c < 6; c++) {
      int ww = w0 + c - 1;
      bool ok = rok && (ww >= 0) && (ww < 64);
      unsigned uv = ok ? *(const unsigned*)&xbufB[((long)(b << 12) + (hh << 6) + ww) * 384 + d0] : 0u;
      v0[r][c] = __uint_as_float(uv << 16);
      v1[r][c] = __uint_as_float(uv & 0xffff0000u);
    }
  }
  #pragma unroll
  for (int i = 0; i < 2; i++) {
    #pragma unroll
    for (int j = 0; j < 4; j++) {
      float a0 = bias.x, a1 = bias.y;
      #pragma unroll
      for (int r = 0; r < 3; r++)
        #pragma unroll
        for (int c = 0; c < 3; c++) {
          a0 += v0[i + r][j + c] * wt0[r * 3 + c];
          a1 += v1[i + r][j + c] * wt1[r * 3 + c];
        }
      float s0 = a0 / (1.f + __expf(-a0));
      float s1 = a1 / (1.f + __expf(-a1));
      __hip_bfloat16 pr[2];
      pr[0] = __float2bfloat16(s0);
      pr[1] = __float2bfloat16(s1);
      *(unsigned*)&xcb[((long)(b << 12) + ((h0 + i) << 6) + (w0 + j)) * 384 + d0] = *(unsigned*)pr;
    }
  }
}

// powers: pws[n] = r^(n+1), log-depth pairing
__device__ __forceinline__ void pow16(float r, float* pws) {
  pws[0] = r;
  #pragma unroll
  for (int n = 1; n < 16; n++) {
    int m = n + 1, c = (m + 1) / 2, f = m - c;
    pws[n] = pws[c - 1] * pws[f - 1];
  }
}

// ---------------- scan pass 0 (+dt fused): 128 segments x 32 steps ----------------
__global__ __launch_bounds__(384) void k_scan0(
    const float* __restrict__ dtsS, const float* __restrict__ BCs,
    const __hip_bfloat16* __restrict__ xcb,
    const float* __restrict__ A_logs, const float* __restrict__ dt_w,
    const float* __restrict__ dt_b,
    __half* __restrict__ dpre, __half* __restrict__ EbH, float* __restrict__ Dend) {
  int bid = blockIdx.x;
  int s = bid & 127, bk = bid >> 7;
  int k = bk & 3, b = bk >> 2;
  int d = threadIdx.x;
  float w[12];
  const float* dwp = dt_w + ((long)(k * 384) + d) * 12;
  #pragma unroll
  for (int r = 0; r < 12; r++) w[r] = dwp[r];
  float db = dt_b[k * 384 + d];
  const float* al = A_logs + ((long)(k * 384) + d) * 16;
  bool pw = true;
  float av[16];
  #pragma unroll
  for (int n = 0; n < 16; n++) {
    float a = __expf(al[n]);
    av[n] = -a;
    pw = pw && (fabsf(a - (float)(n + 1)) < 1e-3f);
  }
  float h[16];
  #pragma unroll
  for (int n = 0; n < 16; n++) h[n] = 0.f;
  float cum = 0.f;
  long bpk = (long)bk << 12;
  long bpix = (long)(b << 12);

  if (pw) {
    #pragma unroll 4
    for (int t = 0; t < 32; t++) {
      int p = dir_pix(k, s * 32 + t);
      const float4* dq = (const float4*)(dtsS + (bpk + p) * 12);
      float4 q0 = dq[0], q1 = dq[1], q2 = dq[2];
      float x = db + q0.x * w[0] + q0.y * w[1] + q0.z * w[2] + q0.w * w[3]
                   + q1.x * w[4] + q1.y * w[5] + q1.z * w[6] + q1.w * w[7]
                   + q2.x * w[8] + q2.y * w[9] + q2.z * w[10] + q2.w * w[11];
      float e = __expf(x);
      float delta = (x > 15.f) ? x : __logf(1.f + e);
      dpre[(bpk + p) * 384 + d] = __float2half(delta);
      float u = __bfloat162float(xcb[(bpix + p) * 384 + d]);
      cum += delta;
      float du = delta * u;
      float rr = __expf(-delta);
      float pws[16]; pow16(rr, pws);
      const float4* Bq = (const float4*)(BCs + (bpk + p) * 32);
      float4 b0 = Bq[0], b1 = Bq[1], b2 = Bq[2], b3 = Bq[3];
      float Bl[16] = {b0.x, b0.y, b0.z, b0.w, b1.x, b1.y, b1.z, b1.w,
                      b2.x, b2.y, b2.z, b2.w, b3.x, b3.y, b3.z, b3.w};
      #pragma unroll
      for (int n = 0; n < 16; n++) h[n] = pws[n] * h[n] + du * Bl[n];
    }
  } else {
    for (int t = 0; t < 32; t++) {
      int p = dir_pix(k, s * 32 + t);
      const float4* dq = (const float4*)(dtsS + (bpk + p) * 12);
      float4 q0 = dq[0], q1 = dq[1], q2 = dq[2];
      float x = db + q0.x * w[0] + q0.y * w[1] + q0.z * w[2] + q0.w * w[3]
                   + q1.x * w[4] + q1.y * w[5] + q1.z * w[6] + q1.w * w[7]
                   + q2.x * w[8] + q2.y * w[9] + q2.z * w[10] + q2.w * w[11];
      float e = __expf(x);
      float delta = (x > 15.f) ? x : __logf(1.f + e);
      dpre[(bpk + p) * 384 + d] = __float2half(delta);
      float u = __bfloat162float(xcb[(bpix + p) * 384 + d]);
      cum += delta;
      float du = delta * u;
      const float4* Bq = (const float4*)(BCs + (bpk + p) * 32);
      float4 b0 = Bq[0], b1 = Bq[1], b2 = Bq[2], b3 = Bq[3];
      float Bl[16] = {b0.x, b0.y, b0.z, b0.w, b1.x, b1.y, b1.z, b1.w,
                      b2.x, b2.y, b2.z, b2.w, b3.x, b3.y, b3.z, b3.w};
      #pragma unroll
      for (int n = 0; n < 16; n++) {
        float dA = __expf(delta * av[n]);
        h[n] = dA * h[n] + du * Bl[n];
      }
    }
  }
  long g = (long)bk * 128 + s;
  __half2* Ep = (__half2*)(EbH + g * 6144 + (long)d * 16);
  #pragma unroll
  for (int n = 0; n < 8; n++) {
    __half2 hv;
    hv.x = __float2half(h[2 * n]);
    hv.y = __float2half(h[2 * n + 1]);
    Ep[n] = hv;
  }
  Dend[g * 384 + d] = cum;
}

// ---------------- combine: Kogge-Stone over 128 segments; fp16 I/O, fp32 internal ----------------
__global__ __launch_bounds__(128) void k_combine(__half* __restrict__ EbH,
                                                 const float* __restrict__ Dend,
                                                 const float* __restrict__ A_logs) {
  int bid = blockIdx.x;            // bk*384 + d, 3072 blocks
  int bk = bid / 384;
  int d = bid - bk * 384;
  int k = bk & 3;
  int s = threadIdx.x;             // segment 0..127
  const float* al = A_logs + ((long)(k * 384) + d) * 16;
  bool pw = true;
  float av[16];
  #pragma unroll
  for (int n = 0; n < 16; n++) {
    float a = __expf(al[n]);
    av[n] = -a;
    pw = pw && (fabsf(a - (float)(n + 1)) < 1e-3f);
  }

  long ebase = ((long)bk * 128 + s) * 6144 + (long)d * 16;
  float e[16];
  {
    const __half2* Ein = (const __half2*)(EbH + ebase);
    #pragma unroll
    for (int n = 0; n < 8; n++) {
      __half2 hv = Ein[n];
      e[2 * n]     = __half2float(hv.x);
      e[2 * n + 1] = __half2float(hv.y);
    }
  }
  float sig = Dend[((long)bk * 128 + s) * 384 + d];

  __shared__ float sE[128][17];    // [s][0]=sigma, [s][1..16]=e
  sE[s][0] = sig;
  #pragma unroll
  for (int n = 0; n < 16; n++) sE[s][1 + n] = e[n];
  __syncthreads();

  for (int o = 1; o < 128; o <<= 1) {
    float ps = 0.f, pe[16];
    bool act = (s >= o);
    if (act) {
      ps = sE[s - o][0];
      #pragma unroll
      for (int n = 0; n < 16; n++) pe[n] = sE[s - o][1 + n];
    }
    __syncthreads();
    if (act) {
      if (pw) {
        float rc = __expf(-sig);
        float pwr[16]; pow16(rc, pwr);      // pwr[n] = exp(av[n]*sig), av[n]=-(n+1)
        #pragma unroll
        for (int n = 0; n < 16; n++) e[n] += pwr[n] * pe[n];
      } else {
        #pragma unroll
        for (int n = 0; n < 16; n++) e[n] += __expf(av[n] * sig) * pe[n];
      }
      sig += ps;
      sE[s][0] = sig;
      #pragma unroll
      for (int n = 0; n < 16; n++) sE[s][1 + n] = e[n];
    }
    __syncthreads();
  }

  float ho[16];
  if (s == 0) {
    #pragma unroll
    for (int n = 0; n < 16; n++) ho[n] = 0.f;
  } else {
    #pragma unroll
    for (int n = 0; n < 16; n++) ho[n] = sE[s - 1][1 + n];
  }
  __half2* Eo = (__half2*)(EbH + ebase);
  #pragma unroll
  for (int n = 0; n < 8; n++) {
    __half2 hv;
    hv.x = __float2half(ho[2 * n]);
    hv.y = __float2half(ho[2 * n + 1]);
    Eo[n] = hv;
  }
}

// ---------------- scan pass 1: full recurrence from h_in (fp16 in EbH) ----------------
// ATOMIC=0: store y bf16 into per-direction plane ybufB. ATOMIC=1: fp32 atomicAdd ysum.
template <int ATOMIC>
__global__ __launch_bounds__(384) void k_scan1(
    const __half* __restrict__ dpre, const float* __restrict__ BCs,
    const __hip_bfloat16* __restrict__ xcb,
    const float* __restrict__ A_logs, const __half* __restrict__ EbH,
    __hip_bfloat16* __restrict__ ybufB, float* __restrict__ ysum) {
  int bid = blockIdx.x;
  int s = bid & 127, bk = bid >> 7;
  int k = bk & 3, b = bk >> 2;
  int d = threadIdx.x;
  const float* al = A_logs + ((long)(k * 384) + d) * 16;
  bool pw = true;
  float av[16];
  #pragma unroll
  for (int n = 0; n < 16; n++) {
    float a = __expf(al[n]);
    av[n] = -a;
    pw = pw && (fabsf(a - (float)(n + 1)) < 1e-3f);
  }
  float h[16];
  {
    const __half2* hp = (const __half2*)(EbH + ((long)bk * 128 + s) * 6144 + (long)d * 16);
    #pragma unroll
    for (int n = 0; n < 8; n++) {
      __half2 hv = hp[n];
      h[2 * n]     = __half2float(hv.x);
      h[2 * n + 1] = __half2float(hv.y);
    }
  }
  long bpk = (long)bk << 12;
  long bpix = (long)(b << 12);

  if (pw) {
    #pragma unroll 4
    for (int t = 0; t < 32; t++) {
      int p = dir_pix(k, s * 32 + t);
      float delta = __half2float(dpre[(bpk + p) * 384 + d]);
      float u = __bfloat162float(xcb[(bpix + p) * 384 + d]);
      float du = delta * u;
      float rr = __expf(-delta);
      float pws[16]; pow16(rr, pws);
      const float4* Bq = (const float4*)(BCs + (bpk + p) * 32);
      float4 b0 = Bq[0], b1 = Bq[1], b2 = Bq[2], b3 = Bq[3];
      float Bl[16] = {b0.x, b0.y, b0.z, b0.w, b1.x, b1.y, b1.z, b1.w,
                      b2.x, b2.y, b2.z, b2.w, b3.x, b3.y, b3.z, b3.w};
      const float4* Cq = Bq + 4;
      float4 c0 = Cq[0], c1 = Cq[1], c2 = Cq[2], c3 = Cq[3];
      float Cl[16] = {c0.x, c0.y, c0.z, c0.w, c1.x, c1.y, c1.z, c1.w,
                      c2.x, c2.y, c2.z, c2.w, c3.x, c3.y, c3.z, c3.w};
      float y = 0.f;
      #pragma unroll
      for (int n = 0; n < 16; n++) { h[n] = pws[n] * h[n] + du * Bl[n]; y += h[n] * Cl[n]; }
      if (ATOMIC) atomicAdd(&ysum[(bpix + p) * 384 + d], y);
      else        ybufB[(bpk + p) * 384 + d] = __float2bfloat16(y);
    }
  } else {
    for (int t = 0; t < 32; t++) {
      int p = dir_pix(k, s * 32 + t);
      float delta = __half2float(dpre[(bpk + p) * 384 + d]);
      float u = __bfloat162float(xcb[(bpix + p) * 384 + d]);
      float du = delta * u;
      const float4* Bq = (const float4*)(BCs + (bpk + p) * 32);
      float4 b0 = Bq[0], b1 = Bq[1], b2 = Bq[2], b3 = Bq[3];
      float Bl[16] = {b0.x, b0.y, b0.z, b0.w, b1.x, b1.y, b1.z, b1.w,
                      b2.x, b2.y, b2.z, b2.w, b3.x, b3.y, b3.z, b3.w};
      const float4* Cq = Bq + 4;
      float4 c0 = Cq[0], c1 = Cq[1], c2 = Cq[2], c3 = Cq[3];
      float Cl[16] = {c0.x, c0.y, c0.z, c0.w, c1.x, c1.y, c1.z, c1.w,
                      c2.x, c2.y, c2.z, c2.w, c3.x, c3.y, c3.z, c3.w};
      float y = 0.f;
      #pragma unroll
      for (int n = 0; n < 16; n++) {
        float dA = __expf(delta * av[n]);
        h[n] = dA * h[n] + du * Bl[n];
        y += h[n] * Cl[n];
      }
      if (ATOMIC) atomicAdd(&ysum[(bpix + p) * 384 + d], y);
      else        ybufB[(bpk + p) * 384 + d] = __float2bfloat16(y);
    }
  }
}

// ---------------- merge (d-paired, 192 thr): y + D-skip + out-LN + silu(z) -> bf16 ----------------
template <int GATHER>
__global__ __launch_bounds__(192) void k_merge(const __hip_bfloat16* __restrict__ yinB,
                                               const float* __restrict__ yinF,
                                               const __hip_bfloat16* __restrict__ xcb,
                                               const __hip_bfloat16* __restrict__ zbufB,
                                               const float* __restrict__ Ds,
                                               const float* __restrict__ g,
                                               const float* __restrict__ be,
                                               __hip_bfloat16* __restrict__ yactb) {
  int row = blockIdx.x;
  int d0 = threadIdx.x * 2;
  float v0, v1;
  if (GATHER) {
    int b = row >> 12, p = row & 4095;
    long base = ((long)(b << 2) << 12) + p;  // plane (b*4+k)*4096 + p
    v0 = 0.f; v1 = 0.f;
    #pragma unroll
    for (int pl = 0; pl < 4; pl++) {
      unsigned uv = *(const unsigned*)&yinB[(base + pl * 4096) * 384 + d0];
      v0 += __uint_as_float(uv << 16);
      v1 += __uint_as_float(uv & 0xffff0000u);
    }
  } else {
    float2 vv = *(const float2*)&yinF[(long)row * 384 + d0];
    v0 = vv.x; v1 = vv.y;
  }
  float2 ds0 = *(const float2*)&Ds[d0];
  float2 ds1 = *(const float2*)&Ds[384 + d0];
  float2 ds2 = *(const float2*)&Ds[768 + d0];
  float2 ds3 = *(const float2*)&Ds[1152 + d0];
  float sd0 = ds0.x + ds1.x + ds2.x + ds3.x;
  float sd1 = ds0.y + ds1.y + ds2.y + ds3.y;
  {
    unsigned uv = *(const unsigned*)&xcb[(long)row * 384 + d0];
    v0 += __uint_as_float(uv << 16) * sd0;
    v1 += __uint_as_float(uv & 0xffff0000u) * sd1;
  }
  float s1 = v0 + v1, s2 = v0 * v0 + v1 * v1;
  #pragma unroll
  for (int o = 32; o > 0; o >>= 1) { s1 += __shfl_xor(s1, o); s2 += __shfl_xor(s2, o); }
  __shared__ float r1[3], r2[3];
  int wv = threadIdx.x >> 6;
  if ((threadIdx.x & 63) == 0) { r1[wv] = s1; r2[wv] = s2; }
  __syncthreads();
  float S1 = r1[0] + r1[1] + r1[2];
  float S2 = r2[0] + r2[1] + r2[2];
  float mu = S1 * (1.f / 384.f);
  float var = S2 * (1.f / 384.f) - mu * mu;
  float rr = rsqrtf(var + 1e-5f);
  float2 gg = *(const float2*)&g[d0];
  float2 bb = *(const float2*)&be[d0];
  float yn0 = (v0 - mu) * rr * gg.x + bb.x;
  float yn1 = (v1 - mu) * rr * gg.y + bb.y;
  unsigned uz = *(const unsigned*)&zbufB[(long)row * 384 + d0];
  float z0 = __uint_as_float(uz << 16);
  float z1 = __uint_as_float(uz & 0xffff0000u);
  float sg0 = z0 / (1.f + __expf(-z0));
  float sg1 = z1 / (1.f + __expf(-z1));
  __hip_bfloat16 pr[2];
  pr[0] = __float2bfloat16(yn0 * sg0);
  pr[1] = __float2bfloat16(yn1 * sg1);
  *(unsigned*)&yactb[(long)row * 384 + d0] = *(unsigned*)pr;
}

extern "C" void kernel_launch(void* const* d_in, const int* in_sizes, int n_in,
                              void* d_out, int out_size, void* d_ws, size_t ws_size,
                              hipStream_t stream) {
  const float* input      = (const float*)d_in[0];
  const float* norm_g     = (const float*)d_in[1];
  const float* norm_b     = (const float*)d_in[2];
  const float* in_proj_w  = (const float*)d_in[3];
  const float* conv_w     = (const float*)d_in[4];
  const float* conv_b     = (const float*)d_in[5];
  const float* x_proj_w   = (const float*)d_in[6];
  const float* dt_w       = (const float*)d_in[7];
  const float* dt_b       = (const float*)d_in[8];
  const float* A_logs     = (const float*)d_in[9];
  const float* Ds         = (const float*)d_in[10];
  const float* out_norm_g = (const float*)d_in[11];
  const float* out_norm_b = (const float*)d_in[12];
  const float* out_proj_w = (const float*)d_in[13];
  float* out = (float*)d_out;

  // plane path total = 24,788,992 floats (~99 MB); atomic fallback = 21,643,264 (~87 MB)
  bool big = ws_size >= (size_t)24788992 * 4;

  float* ws = (float*)d_ws;
  long o = 0;
  __hip_bfloat16* xnb   = (__hip_bfloat16*)(ws + o); o += 786432;   // 8192x192 bf16
  __hip_bfloat16* xbufB = (__hip_bfloat16*)(ws + o); o += 1572864;  // 8192x384 bf16
  __hip_bfloat16* zbufB = (__hip_bfloat16*)(ws + o); o += 1572864;
  __hip_bfloat16* xcb   = (__hip_bfloat16*)(ws + o); o += 1572864;
  __hip_bfloat16* Wt1   = (__hip_bfloat16*)(ws + o); o += 73728;    // 768x192 bf16
  __hip_bfloat16* Wt2   = (__hip_bfloat16*)(ws + o); o += 36864;
  __hip_bfloat16* Wt3   = (__hip_bfloat16*)(ws + o); o += 36864;
  float* dtsS           = ws + o;                    o += 393216;   // (BK,p,12) pixel order
  float* BCs            = ws + o;                    o += 1048576;  // (BK,p,32): B|C interleaved
  __half* dpre          = (__half*)(ws + o);         o += 6291456;  // (BK,p,384) fp16 delta
  __half* EbH           = (__half*)(ws + o);         o += 3145728;  // (1024 segs, 6144) fp16
  float* Dend           = ws + o;                    o += 393216;   // (1024, 384) fp32
  __hip_bfloat16* ybufB = (__hip_bfloat16*)(ws + o);
  float* ysum           = ws + o;                    o += big ? 6291456 : 3145728;
  __hip_bfloat16* yactb = (__hip_bfloat16*)(ws + o); o += 1572864;

  k_lnpackw<<<dim3(3200), dim3(256), 0, stream>>>(input, norm_g, norm_b, xnb,
                                                  in_proj_w, x_proj_w, out_proj_w, Wt1, Wt2, Wt3);
  k_gemm_mfma<2, 192><<<dim3(4, 128), dim3(256), 0, stream>>>(xnb, Wt1, nullptr, nullptr, xbufB, zbufB,
                                                              nullptr, nullptr, 8192, 768, 192);
  k_conv<<<dim3(1024), dim3(192), 0, stream>>>(xbufB, conv_w, conv_b, xcb);
  k_gemm_mfma<3, 64><<<dim3(3, 128), dim3(256), 0, stream>>>(xcb, Wt2, nullptr, nullptr, nullptr, nullptr,
                                                             dtsS, BCs, 8192, 192, 384);
  k_scan0<<<dim3(1024), dim3(384), 0, stream>>>(dtsS, BCs, xcb, A_logs, dt_w, dt_b,
                                                dpre, EbH, Dend);
  k_combine<<<dim3(3072), dim3(128), 0, stream>>>(EbH, Dend, A_logs);
  if (big) {
    k_scan1<0><<<dim3(1024), dim3(384), 0, stream>>>(dpre, BCs, xcb, A_logs, EbH, ybufB, nullptr);
    k_merge<1><<<dim3(8192), dim3(192), 0, stream>>>(ybufB, nullptr, xcb, zbufB, Ds,
                                                     out_norm_g, out_norm_b, yactb);
  } else {
    hipMemsetAsync(ysum, 0, (size_t)3145728 * 4, stream);
    k_scan1<1><<<dim3(1024), dim3(384), 0, stream>>>(dpre, BCs, xcb, A_logs, EbH, nullptr, ysum);
    k_merge<0><<<dim3(8192), dim3(192), 0, stream>>>(nullptr, ysum, xcb, zbufB, Ds,
                                                     out_norm_g, out_norm_b, yactb);
  }
  k_gemm_mfma<1, 64><<<dim3(3, 128), dim3(256), 0, stream>>>(yactb, Wt3, input, out, nullptr, nullptr,
                                                             nullptr, nullptr, 8192, 192, 384);
}